// Round 5
// baseline (284.029 us; speedup 1.0000x reference)
//
#include <hip/hip_runtime.h>
#include <hip/hip_bf16.h>

// Attention: out = softmax_causal((xWq+bq)(xWk+bk)^T / sqrt(D)) (xWv+bv) Wo + bo
// B=4, S=2048, D=1024.  All GEMMs bf16 MFMA 16x16x32, fp32 accumulate.
// R5: 256x256-tile 8-wave GEMM, BK=32, FOUR LDS buffers (128 KiB), stage-ahead-2
//     pipeline with one counted vmcnt(4) + one barrier per K-tile (loads issued
//     2 tiles (~1200cyc) before their wait -> wait is a no-op in steady state).
//     LDS swizzle cb^=((r>>1)&3)<<4 (2-way = free), inverse-swizzled global src.
//     PV K-split into <=1024-deep chunks (fp32 partials + merge) to kill the
//     92us serial deep-block.  XCD swizzle on QKV grid.

typedef __bf16 bf16x8 __attribute__((ext_vector_type(8)));
typedef __bf16 bf16x4 __attribute__((ext_vector_type(4)));
typedef float  f32x4  __attribute__((ext_vector_type(4)));

#define BDIM 1024
#define SDIM 2048
#define BATCH 4

__device__ __forceinline__ void gload_lds16(const void* g, void* l) {
    __builtin_amdgcn_global_load_lds(
        (const __attribute__((address_space(1))) void*)g,
        (__attribute__((address_space(3))) void*)l, 16, 0, 0);
}

// ---------------- fp32 -> bf16 elementwise ----------------
__global__ __launch_bounds__(256) void cvt_f32_bf16(const float* __restrict__ in,
                                                    __bf16* __restrict__ out, long n) {
    long i = ((long)blockIdx.x * 256 + threadIdx.x) * 4;
    if (i + 3 < n) {
        float4 v = *(const float4*)(in + i);
        bf16x4 o;
        o[0] = (__bf16)v.x; o[1] = (__bf16)v.y; o[2] = (__bf16)v.z; o[3] = (__bf16)v.w;
        *(bf16x4*)(out + i) = o;
    }
}

// ---------------- bias concat [bq|bk|bv] -> bcat[3072] ----------------
__global__ __launch_bounds__(256) void concat3(const float* __restrict__ a,
                                               const float* __restrict__ b,
                                               const float* __restrict__ c,
                                               float* __restrict__ o) {
    int i = blockIdx.x * 256 + threadIdx.x;
    if (i < 3072)
        o[i] = (i < 1024) ? a[i] : ((i < 2048) ? b[i - 1024] : c[i - 2048]);
}

// ---------------- transpose (fp32 or bf16 in) -> bf16 out ----------------
template <typename Tin>
__global__ __launch_bounds__(256) void transpose_to_bf16(const Tin* __restrict__ in,
                                                         __bf16* __restrict__ out,
                                                         int ldIn, int ldOut,
                                                         long sIn, long sOut) {
    __shared__ float tile[32][33];
    const long b = blockIdx.z;
    in += b * sIn; out += b * sOut;
    const int r0 = blockIdx.y * 32, c0 = blockIdx.x * 32;
    const int tx = threadIdx.x, ty = threadIdx.y;  // block (32,8)
    #pragma unroll
    for (int j = ty; j < 32; j += 8)
        tile[j][tx] = (float)in[(long)(r0 + j) * ldIn + (c0 + tx)];
    __syncthreads();
    #pragma unroll
    for (int j = ty; j < 32; j += 8)
        out[(long)(c0 + j) * ldOut + (r0 + tx)] = (__bf16)tile[tx][j];
}

// ------------- 256x256 BT GEMM, BK=32, 4-deep pipelined ----------------------
// 8 waves (2M x 4N), per-wave 128x64 output = acc[8][4].
// LDS: As[4][256*32] + Bs[4][256*32] bf16 = 128 KiB (1 block/CU).
// Pipeline: compute tile t from buf t&3 while tile t+1 is landed and tile t+2's
// loads are in flight; boundary = s_waitcnt vmcnt(4) + s_barrier (counted: only
// requires t+1 landed, leaves t+2's 4 loads flying).  Stage(t+2) overwrites the
// buf last read at t-2 (two barriers earlier) -> race-free.
// Swizzle: 64-B LDS rows; col-byte ^= ((r>>1)&3)<<4 -> 2 lanes/bank (free).
// Inverse swizzle applied to per-lane GLOBAL source (rule #21).
// PVMODE: bz = batch*2 + chunk; K-range = [chunk*1024, min((by+1)*256, +1024));
//         chunk0 -> C0 (fp32 main), chunk1 -> C1 (fp32 extra, rows-1024).
template <typename Tout, bool CSKIP, bool PVMODE, bool SWZ>
__global__ __launch_bounds__(512, 2) void gemm_p(const __bf16* __restrict__ Ag,
                                                 const __bf16* __restrict__ Bg,
                                                 Tout* __restrict__ C0,
                                                 float* __restrict__ C1,
                                                 const float* __restrict__ bias,
                                                 int K, int lda, int ldb, int ldc,
                                                 int nbx, long sA, long sB, long sC) {
    int bx, by;
    const int bz = blockIdx.z;
    if (SWZ) {  // XCD-aware: 8 XCDs each get a contiguous chunk of tile space
        const int flat = blockIdx.x;
        const int w = (flat & 7) * ((int)gridDim.x >> 3) + (flat >> 3);
        bx = w % nbx; by = w / nbx;
    } else { bx = blockIdx.x; by = blockIdx.y; }
    if (CSKIP && bx > by) return;  // tile fully above causal diagonal

    const int m0 = by * 256, n0 = bx * 256;
    int kStart = 0, kEnd = K;
    const __bf16* A; const __bf16* B;
    Tout* C;
    if (PVMODE) {
        const int b = bz >> 1, chunk = bz & 1;
        kStart = chunk << 10;
        kEnd = min((by + 1) * 256, kStart + 1024);
        if (kEnd <= kStart) return;       // by<4 has no chunk1
        A = Ag + (long)b * sA;
        B = Bg + (long)b * sB;
        C = chunk ? (Tout*)(C1 + ((long)b - 1) * 1048576)  // rows shifted by -1024
                  : C0 + (long)b * sC;
    } else {
        A = Ag + (long)bz * sA;
        B = Bg + (long)bz * sB;
        C = C0 + (long)bz * sC;
    }
    const int nt = (kEnd - kStart) >> 5;

    __shared__ __align__(16) __bf16 As[4][8192];
    __shared__ __align__(16) __bf16 Bs[4][8192];

    const int tid = threadIdx.x;
    const int wid = tid >> 6, l = tid & 63;
    const int wm = wid >> 2, wn = wid & 3;       // wave grid 2(M) x 4(N)

    // staging: thread covers LDS bytes {tid*16, 8192+tid*16} per operand-tile.
    // inverse-swizzle the global column so a linear LDS write yields the
    // swizzled layout.
    int srcA[2], srcB[2];
    #pragma unroll
    for (int i = 0; i < 2; ++i) {
        const int beta = i * 8192 + tid * 16;                 // LDS byte
        const int r = beta >> 6;                               // logical row
        const int ce = ((beta & 48) ^ (((r >> 1) & 3) << 4)) >> 1;  // col elem
        srcA[i] = (m0 + r) * lda + ce;
        srcB[i] = (n0 + r) * ldb + ce;
    }
    const int ldst = wid * 512;  // elems; wave-uniform base (HW adds lane*16B)

    auto stage = [&](int buf, int koff) {
        #pragma unroll
        for (int i = 0; i < 2; ++i) {
            gload_lds16(A + srcA[i] + koff, &As[buf][i * 4096 + ldst]);
            gload_lds16(B + srcB[i] + koff, &Bs[buf][i * 4096 + ldst]);
        }
    };

    // swizzled fragment read offsets (elems), constant per lane:
    const int off = (((l >> 4) * 16) ^ ((((l & 15) >> 1) & 3) << 4)) >> 1;
    const int aOff = (wm * 128 + (l & 15)) * 32 + off;
    const int bOff = (wn * 64 + (l & 15)) * 32 + off;

    f32x4 acc[8][4] = {};

    auto compute = [&](int buf) {
        bf16x8 bfr[4], afr[4];
        #pragma unroll
        for (int n = 0; n < 4; ++n) bfr[n] = *(const bf16x8*)&Bs[buf][bOff + n * 512];
        #pragma unroll
        for (int m = 0; m < 4; ++m) afr[m] = *(const bf16x8*)&As[buf][aOff + m * 512];
        __builtin_amdgcn_s_setprio(1);
        #pragma unroll
        for (int m = 0; m < 4; ++m)
            #pragma unroll
            for (int n = 0; n < 4; ++n)
                acc[m][n] = __builtin_amdgcn_mfma_f32_16x16x32_bf16(afr[m], bfr[n],
                                                                    acc[m][n], 0, 0, 0);
        __builtin_amdgcn_s_setprio(0);
        #pragma unroll
        for (int m = 0; m < 4; ++m) afr[m] = *(const bf16x8*)&As[buf][aOff + (4 + m) * 512];
        __builtin_amdgcn_s_setprio(1);
        #pragma unroll
        for (int m = 0; m < 4; ++m)
            #pragma unroll
            for (int n = 0; n < 4; ++n)
                acc[4 + m][n] = __builtin_amdgcn_mfma_f32_16x16x32_bf16(afr[m], bfr[n],
                                                                        acc[4 + m][n], 0, 0, 0);
        __builtin_amdgcn_s_setprio(0);
    };

    // prologue: tiles 0,1 issued; wait tile 0 only (tile 1's 4 loads stay out)
    stage(0, kStart);
    stage(1, kStart + 32);
    asm volatile("s_waitcnt vmcnt(4)" ::: "memory");
    __builtin_amdgcn_s_barrier();
    asm volatile("" ::: "memory");

    for (int t = 0; t < nt; ++t) {
        if (t + 2 < nt) stage((t + 2) & 3, kStart + (t + 2) * 32);
        compute(t & 3);
        if (t + 1 < nt) {
            if (t + 2 < nt) asm volatile("s_waitcnt vmcnt(4)" ::: "memory");
            else            asm volatile("s_waitcnt vmcnt(0)" ::: "memory");
            __builtin_amdgcn_s_barrier();
            asm volatile("" ::: "memory");
        }
    }

    // epilogue: C/D layout col = lane&15, row = (lane>>4)*4 + reg [m89-verified]
    const int rb = (l >> 4) * 4, cl = l & 15;
    #pragma unroll
    for (int n = 0; n < 4; ++n) {
        const int col = n0 + wn * 64 + n * 16 + cl;
        const float bv = bias ? bias[col] : 0.f;
        #pragma unroll
        for (int m = 0; m < 8; ++m) {
            const int row = m0 + wm * 128 + m * 16 + rb;
            #pragma unroll
            for (int r = 0; r < 4; ++r)
                C[(long)(row + r) * ldc + col] = (Tout)(acc[m][n][r] + bv);
        }
    }
}

// ---------------- merge PV partials: ctxb = bf16(main + extra?) --------------
// main: [B][2048][1024] fp32; extra: [B][1024][1024] fp32 (rows 1024.. only).
__global__ __launch_bounds__(256) void merge_ctx(const float* __restrict__ mainp,
                                                 const float* __restrict__ extrap,
                                                 __bf16* __restrict__ out) {
    const long i = ((long)blockIdx.x * 256 + threadIdx.x) * 4;
    float4 v = *(const float4*)(mainp + i);
    const long b = i >> 21;                 // 2048*1024 per batch
    const long m = (i >> 10) & 2047;
    if (m >= 1024) {
        const float4 e = *(const float4*)(extrap + (i - (b + 1) * 1048576));
        v.x += e.x; v.y += e.y; v.z += e.z; v.w += e.w;
    }
    bf16x4 o;
    o[0] = (__bf16)v.x; o[1] = (__bf16)v.y; o[2] = (__bf16)v.z; o[3] = (__bf16)v.w;
    *(bf16x4*)(out + i) = o;
}

// ---------------- causal softmax row kernel (16B/lane) ----------------
__global__ __launch_bounds__(256) void softmax_causal(const __bf16* __restrict__ scores,
                                                      __bf16* __restrict__ P, float scale) {
    const int q = blockIdx.x;
    const long b = blockIdx.y;
    const __bf16* srow = scores + (b * SDIM + q) * (long)SDIM;
    __bf16* prow = P + (b * SDIM + q) * (long)SDIM;
    const int n = q + 1;
    const int tid = threadIdx.x;
    const int k0 = tid * 8;
    __shared__ float red[8];

    const bf16x8 v = *(const bf16x8*)(srow + k0);
    float vals[8];
    float mx = -1e30f;
    #pragma unroll
    for (int i = 0; i < 8; ++i) {
        const float s = (k0 + i < n) ? (float)v[i] * scale : -1e30f;
        vals[i] = s;
        mx = fmaxf(mx, s);
    }
    #pragma unroll
    for (int o = 32; o > 0; o >>= 1) mx = fmaxf(mx, __shfl_xor(mx, o));
    if ((tid & 63) == 0) red[tid >> 6] = mx;
    __syncthreads();
    mx = fmaxf(fmaxf(red[0], red[1]), fmaxf(red[2], red[3]));

    float p[8];
    float sum = 0.f;
    #pragma unroll
    for (int i = 0; i < 8; ++i) {
        p[i] = __expf(vals[i] - mx);
        sum += p[i];
    }
    #pragma unroll
    for (int o = 32; o > 0; o >>= 1) sum += __shfl_xor(sum, o);
    if ((tid & 63) == 0) red[4 + (tid >> 6)] = sum;
    __syncthreads();
    sum = red[4] + red[5] + red[6] + red[7];

    const float inv = 1.f / sum;
    bf16x8 o;
    #pragma unroll
    for (int i = 0; i < 8; ++i)
        o[i] = (__bf16)((k0 + i < n) ? p[i] * inv : 0.f);
    *(bf16x8*)(prow + k0) = o;
}

extern "C" void kernel_launch(void* const* d_in, const int* in_sizes, int n_in,
                              void* d_out, int out_size, void* d_ws, size_t ws_size,
                              hipStream_t stream) {
    const float* x  = (const float*)d_in[0];
    // d_in[1] = mask (tril ones) -- causality enforced by index, unused.
    const float* Wq = (const float*)d_in[2];
    const float* bq = (const float*)d_in[3];
    const float* Wk = (const float*)d_in[4];
    const float* bk = (const float*)d_in[5];
    const float* Wv = (const float*)d_in[6];
    const float* bv = (const float*)d_in[7];
    const float* Wo = (const float*)d_in[8];
    const float* bo = (const float*)d_in[9];
    float* out = (float*)d_out;

    char* ws = (char*)d_ws;
    const long MT = (long)BATCH * SDIM;           // 8192 rows
    const long XE = MT * BDIM;
    // workspace (bytes); lifetimes annotated
    __bf16* xb    = (__bf16*)(ws);                // 16 MiB, dead after QKV
    __bf16* Wcat  = (__bf16*)(ws + 16777216);     // 6 MiB
    __bf16* Wot   = (__bf16*)(ws + 23068672);     // 2 MiB
    float*  bcat  = (float*)(ws + 25165824);      // 12 KiB
    __bf16* QKVb  = (__bf16*)(ws + 25178112);     // 48 MiB (8192 x 3072)
    __bf16* Vtb   = (__bf16*)(ws + 75509760);     // 16 MiB (B x [1024][2048])
    __bf16* Sc    = (__bf16*)(ws + 92286976);     // 32 MiB, dead after softmax
    __bf16* Pb    = (__bf16*)(ws + 25178112);     // alias QKVb[0..32M)
    float*  ctxM  = (float*)(ws + 92286976);      // 32 MiB fp32, alias Sc
    float*  ctxE  = (float*)(ws);                 // 16 MiB fp32, alias xb
    __bf16* ctxb  = (__bf16*)(ws + 58732544);     // 16 MiB, alias QKVb[32M..48M)

    const long SD  = (long)SDIM * BDIM;           // 2,097,152
    const long SS  = (long)SDIM * SDIM;           // 4,194,304
    const long SQ3 = (long)SDIM * 3 * BDIM;       // 6,291,456

    cvt_f32_bf16<<<dim3((unsigned)(XE / 4 / 256)), 256, 0, stream>>>(x, xb, XE);
    transpose_to_bf16<float><<<dim3(32, 32, 1), dim3(32, 8), 0, stream>>>(Wq, Wcat,             BDIM, BDIM, 0, 0);
    transpose_to_bf16<float><<<dim3(32, 32, 1), dim3(32, 8), 0, stream>>>(Wk, Wcat + 1024*1024, BDIM, BDIM, 0, 0);
    transpose_to_bf16<float><<<dim3(32, 32, 1), dim3(32, 8), 0, stream>>>(Wv, Wcat + 2048*1024, BDIM, BDIM, 0, 0);
    transpose_to_bf16<float><<<dim3(32, 32, 1), dim3(32, 8), 0, stream>>>(Wo, Wot,              BDIM, BDIM, 0, 0);
    concat3<<<dim3(12), 256, 0, stream>>>(bq, bk, bv, bcat);

    // QKV[8192][3072] = x @ Wcat^T + bcat   (384 blocks, XCD-swizzled, nbx=12)
    gemm_p<__bf16, false, false, true><<<dim3(384, 1, 1), 512, 0, stream>>>(
        xb, Wcat, QKVb, nullptr, bcat, BDIM, BDIM, BDIM, 3072, 12, 0, 0, 0);
    // V^T per batch: [S,1024] (stride 3072) -> [1024][S]
    transpose_to_bf16<__bf16><<<dim3(32, 64, BATCH), dim3(32, 8), 0, stream>>>(
        QKVb + 2048, Vtb, 3072, SDIM, SQ3, SD);
    // scores = Q @ K^T per batch (causal tile skip)
    gemm_p<__bf16, true, false, false><<<dim3(8, 8, BATCH), 512, 0, stream>>>(
        QKVb, QKVb + 1024, Sc, nullptr, nullptr, BDIM, 3072, 3072, SDIM, 8, SQ3, SQ3, SS);
    // causal softmax (scale = 1/32)
    softmax_causal<<<dim3(SDIM, BATCH), 256, 0, stream>>>(Sc, Pb, 0.03125f);
    // ctx = P @ V, K split into <=1024 chunks: bz = batch*2 + chunk (256 blocks)
    gemm_p<float, false, true, false><<<dim3(4, 8, 2 * BATCH), 512, 0, stream>>>(
        Pb, Vtb, ctxM, ctxE, nullptr, SDIM, SDIM, SDIM, BDIM, 4, SS, SD, SD);
    // merge partials -> bf16 ctx
    merge_ctx<<<dim3((unsigned)(XE / 4 / 256)), 256, 0, stream>>>(ctxM, ctxE, ctxb);
    // out = ctx @ Wo + bo (fp32 out)
    gemm_p<float, false, false, false><<<dim3(4, 32, 1), 512, 0, stream>>>(
        ctxb, Wot, out, nullptr, bo, BDIM, BDIM, BDIM, BDIM, 4, 0, 0, 0);
}

// Round 6
// 256.098 us; speedup vs baseline: 1.1091x; 1.1091x over previous
//
#include <hip/hip_runtime.h>
#include <hip/hip_bf16.h>

// Attention: out = softmax_causal((xWq+bq)(xWk+bk)^T / sqrt(D)) (xWv+bv) Wo + bo
// B=4, S=2048, D=1024.  All GEMMs bf16 MFMA 16x16x32, fp32 accumulate.
// R6: 8-phase-style schedule (4 phases per BK=64 K-tile), per-phase
//     {ds_read | stage-half-tile | barrier | 16 MFMA | barrier}, counted
//     vmcnt(8) once per K-tile (never 0 mid-loop), staging 2 K-tiles ahead.
//     LDS 2 x (A 256x64 + B 256x64) = 128 KiB.  G4 swizzle byte^=(row&7)<<4
//     (rows are 128B), inverse-swizzled global source (rule #21).

typedef __bf16 bf16x8 __attribute__((ext_vector_type(8)));
typedef __bf16 bf16x4 __attribute__((ext_vector_type(4)));
typedef float  f32x4  __attribute__((ext_vector_type(4)));

#define BDIM 1024
#define SDIM 2048
#define BATCH 4

#define BAR()  do { asm volatile("" ::: "memory"); __builtin_amdgcn_s_barrier(); \
                    asm volatile("" ::: "memory"); } while (0)
#define SCB()  __builtin_amdgcn_sched_barrier(0)

__device__ __forceinline__ void gload_lds16(const void* g, void* l) {
    __builtin_amdgcn_global_load_lds(
        (const __attribute__((address_space(1))) void*)g,
        (__attribute__((address_space(3))) void*)l, 16, 0, 0);
}

// ---------------- fp32 -> bf16 elementwise ----------------
__global__ __launch_bounds__(256) void cvt_f32_bf16(const float* __restrict__ in,
                                                    __bf16* __restrict__ out, long n) {
    long i = ((long)blockIdx.x * 256 + threadIdx.x) * 4;
    if (i + 3 < n) {
        float4 v = *(const float4*)(in + i);
        bf16x4 o;
        o[0] = (__bf16)v.x; o[1] = (__bf16)v.y; o[2] = (__bf16)v.z; o[3] = (__bf16)v.w;
        *(bf16x4*)(out + i) = o;
    }
}

// ---------------- bias concat [bq|bk|bv] -> bcat[3072] ----------------
__global__ __launch_bounds__(256) void concat3(const float* __restrict__ a,
                                               const float* __restrict__ b,
                                               const float* __restrict__ c,
                                               float* __restrict__ o) {
    int i = blockIdx.x * 256 + threadIdx.x;
    if (i < 3072)
        o[i] = (i < 1024) ? a[i] : ((i < 2048) ? b[i - 1024] : c[i - 2048]);
}

// ---------------- transpose (fp32 or bf16 in) -> bf16 out ----------------
template <typename Tin>
__global__ __launch_bounds__(256) void transpose_to_bf16(const Tin* __restrict__ in,
                                                         __bf16* __restrict__ out,
                                                         int ldIn, int ldOut,
                                                         long sIn, long sOut) {
    __shared__ float tile[32][33];
    const long b = blockIdx.z;
    in += b * sIn; out += b * sOut;
    const int r0 = blockIdx.y * 32, c0 = blockIdx.x * 32;
    const int tx = threadIdx.x, ty = threadIdx.y;  // block (32,8)
    #pragma unroll
    for (int j = ty; j < 32; j += 8)
        tile[j][tx] = (float)in[(long)(r0 + j) * ldIn + (c0 + tx)];
    __syncthreads();
    #pragma unroll
    for (int j = ty; j < 32; j += 8)
        out[(long)(c0 + j) * ldOut + (r0 + tx)] = (__bf16)tile[tx][j];
}

// ------------- 256x256 BT GEMM, BK=64, 4-phase/K-tile schedule ---------------
// 8 waves (2M x 4N), per-wave 128x64 output = acc[8][4].
// LDS: As[2][256*64] + Bs[2][256*64] bf16 = 128 KiB; buffer = K-tile parity.
// Staging runs 2 K-tiles ahead (A-half in PH2, B-half in PH3); one counted
// s_waitcnt vmcnt(8) per K-tile; lgkmcnt(0)-before-barrier at end of PH1 makes
// the PH2/PH3 overwrite of the current buffer race-free (all reads complete
// block-wide before any staging write is issued).
// Swizzle: 128B LDS rows; byte ^= ((row&7)<<4); inverse on global source.
// PVMODE: bz = batch*2 + chunk; K-range = [chunk*1024, min((by+1)*256,+1024));
//         chunk0 -> C0 (fp32 main), chunk1 -> C1 (fp32 extra, rows-1024).
template <typename Tout, bool CSKIP, bool PVMODE, bool SWZ>
__global__ __launch_bounds__(512, 2) void gemm8p(const __bf16* __restrict__ Ag,
                                                 const __bf16* __restrict__ Bg,
                                                 Tout* __restrict__ C0,
                                                 float* __restrict__ C1,
                                                 const float* __restrict__ bias,
                                                 int K, int lda, int ldb, int ldc,
                                                 int nbx, long sA, long sB, long sC) {
    int bx, by;
    const int bz = blockIdx.z;
    if (SWZ) {  // XCD-aware contiguous chunks (grid.x % 8 == 0)
        const int flat = blockIdx.x;
        const int w = (flat & 7) * ((int)gridDim.x >> 3) + (flat >> 3);
        bx = w % nbx; by = w / nbx;
    } else { bx = blockIdx.x; by = blockIdx.y; }
    if (CSKIP && bx > by) return;  // tile fully above causal diagonal

    const int m0 = by * 256, n0 = bx * 256;
    int kStart = 0, kEnd = K;
    const __bf16* A; const __bf16* B;
    Tout* C;
    if (PVMODE) {
        const int b = bz >> 1, chunk = bz & 1;
        kStart = chunk << 10;
        kEnd = min((by + 1) * 256, kStart + 1024);
        if (kEnd <= kStart) return;       // by<4 has no chunk1
        A = Ag + (long)b * sA;
        B = Bg + (long)b * sB;
        C = chunk ? (Tout*)(C1 + ((long)b - 1) * 1048576)  // rows shifted -1024
                  : C0 + (long)b * sC;
    } else {
        A = Ag + (long)bz * sA;
        B = Bg + (long)bz * sB;
        C = C0 + (long)bz * sC;
    }
    const int NT = (kEnd - kStart) >> 6;   // BK=64 tiles

    __shared__ __align__(16) __bf16 As[2][16384];  // [256][64]
    __shared__ __align__(16) __bf16 Bs[2][16384];

    const int tid = threadIdx.x;
    const int wid = tid >> 6, l = tid & 63;
    const int wm = wid >> 2, wn = wid & 3;          // wave grid 2(M) x 4(N)
    const int lr = l & 15, lu = l >> 4;

    // ---- staging source offsets (inverse-swizzled global cols, rule #21) ----
    int srcA[4], srcB[4];
    #pragma unroll
    for (int i = 0; i < 4; ++i) {
        const int beta = i * 8192 + tid * 16;          // linear LDS byte
        const int r = beta >> 7;                       // row 0..255 (128B rows)
        const int cb = (beta & 127) ^ ((r & 7) << 4);  // unswizzled col byte
        srcA[i] = (m0 + r) * lda + (cb >> 1);
        srcB[i] = (n0 + r) * ldb + (cb >> 1);
    }
    auto stageA = [&](int buf, int koff) {
        #pragma unroll
        for (int i = 0; i < 4; ++i)
            gload_lds16(A + srcA[i] + koff, (char*)&As[buf][0] + i * 8192 + wid * 1024);
    };
    auto stageB = [&](int buf, int koff) {
        #pragma unroll
        for (int i = 0; i < 4; ++i)
            gload_lds16(B + srcB[i] + koff, (char*)&Bs[buf][0] + i * 8192 + wid * 1024);
    };

    // ---- swizzled fragment read offsets (elements), lane constants ----
    const int xo  = (lr & 7) << 4;                       // row-derived XOR (bytes)
    const int c0e = ((lu << 4) ^ xo) >> 1;               // kk=0 col
    const int c1e = ((64 + (lu << 4)) ^ xo) >> 1;        // kk=1 col
    const int aBase = (wm * 128 + lr) * 64;
    const int bBase = (wn * 64 + lr) * 64;

    f32x4 acc[8][4] = {};

    // ---- prologue: tiles 0 and 1 staged; tile 0 must be landed ----
    stageA(0, kStart); stageB(0, kStart);
    if (NT > 1) { stageA(1, kStart + 64); stageB(1, kStart + 64); }
    if (NT > 1) asm volatile("s_waitcnt vmcnt(8)" ::: "memory");
    else        asm volatile("s_waitcnt vmcnt(0)" ::: "memory");
    BAR();

    for (int T = 0; T < NT; ++T) {
        const int c = T & 1;
        const __bf16* Ab = &As[c][0];
        const __bf16* Bb = &Bs[c][0];
        bf16x8 aL0[4], aL1[4], aH0[4], aH1[4], bF0[4], bF1[4];

        // ---- PH0: read A(m0-3) + B (16 ds_read_b128) | MFMA m0-3 kk0 ----
        #pragma unroll
        for (int m = 0; m < 4; ++m) aL0[m] = *(const bf16x8*)(Ab + aBase + m * 1024 + c0e);
        #pragma unroll
        for (int n = 0; n < 4; ++n) bF0[n] = *(const bf16x8*)(Bb + bBase + n * 1024 + c0e);
        #pragma unroll
        for (int m = 0; m < 4; ++m) aL1[m] = *(const bf16x8*)(Ab + aBase + m * 1024 + c1e);
        #pragma unroll
        for (int n = 0; n < 4; ++n) bF1[n] = *(const bf16x8*)(Bb + bBase + n * 1024 + c1e);
        BAR(); SCB();
        __builtin_amdgcn_s_setprio(1);
        #pragma unroll
        for (int m = 0; m < 4; ++m)
            #pragma unroll
            for (int n = 0; n < 4; ++n)
                acc[m][n] = __builtin_amdgcn_mfma_f32_16x16x32_bf16(aL0[m], bF0[n],
                                                                    acc[m][n], 0, 0, 0);
        __builtin_amdgcn_s_setprio(0); SCB();
        BAR();

        // ---- PH1: read A(m4-7) (8 reads) | MFMA m0-3 kk1 | drain lgkm ----
        #pragma unroll
        for (int m = 0; m < 4; ++m) aH0[m] = *(const bf16x8*)(Ab + aBase + (4 + m) * 1024 + c0e);
        #pragma unroll
        for (int m = 0; m < 4; ++m) aH1[m] = *(const bf16x8*)(Ab + aBase + (4 + m) * 1024 + c1e);
        BAR(); SCB();
        __builtin_amdgcn_s_setprio(1);
        #pragma unroll
        for (int m = 0; m < 4; ++m)
            #pragma unroll
            for (int n = 0; n < 4; ++n)
                acc[m][n] = __builtin_amdgcn_mfma_f32_16x16x32_bf16(aL1[m], bF1[n],
                                                                    acc[m][n], 0, 0, 0);
        __builtin_amdgcn_s_setprio(0); SCB();
        asm volatile("s_waitcnt lgkmcnt(0)" ::: "memory");  // ALL reads of buf c done
        SCB();
        BAR();  // after this barrier, overwriting buf c is race-free block-wide

        // ---- PH2: stage A-half of T+2 | MFMA m4-7 kk0 ----
        if (T + 2 < NT) stageA(c, kStart + (T + 2) * 64);
        SCB();
        __builtin_amdgcn_s_setprio(1);
        #pragma unroll
        for (int m = 0; m < 4; ++m)
            #pragma unroll
            for (int n = 0; n < 4; ++n)
                acc[4 + m][n] = __builtin_amdgcn_mfma_f32_16x16x32_bf16(aH0[m], bF0[n],
                                                                        acc[4 + m][n], 0, 0, 0);
        __builtin_amdgcn_s_setprio(0); SCB();
        BAR();

        // ---- PH3: stage B-half of T+2 | MFMA m4-7 kk1 | counted vmcnt ----
        if (T + 2 < NT) stageB(c, kStart + (T + 2) * 64);
        SCB();
        __builtin_amdgcn_s_setprio(1);
        #pragma unroll
        for (int m = 0; m < 4; ++m)
            #pragma unroll
            for (int n = 0; n < 4; ++n)
                acc[4 + m][n] = __builtin_amdgcn_mfma_f32_16x16x32_bf16(aH1[m], bF1[n],
                                                                        acc[4 + m][n], 0, 0, 0);
        __builtin_amdgcn_s_setprio(0); SCB();
        if (T + 1 < NT) {
            if (T + 2 < NT) asm volatile("s_waitcnt vmcnt(8)" ::: "memory");
            else            asm volatile("s_waitcnt vmcnt(0)" ::: "memory");
            BAR();
        }
    }

    // epilogue: C/D layout col = lane&15, row = (lane>>4)*4 + reg [m89-verified]
    const int rb = (l >> 4) * 4, cl = l & 15;
    #pragma unroll
    for (int n = 0; n < 4; ++n) {
        const int col = n0 + wn * 64 + n * 16 + cl;
        const float bvv = bias ? bias[col] : 0.f;
        #pragma unroll
        for (int m = 0; m < 8; ++m) {
            const int row = m0 + wm * 128 + m * 16 + rb;
            #pragma unroll
            for (int r = 0; r < 4; ++r)
                C[(long)(row + r) * ldc + col] = (Tout)(acc[m][n][r] + bvv);
        }
    }
}

// ---------------- merge PV partials: ctxb = bf16(main + extra?) --------------
__global__ __launch_bounds__(256) void merge_ctx(const float* __restrict__ mainp,
                                                 const float* __restrict__ extrap,
                                                 __bf16* __restrict__ out) {
    const long i = ((long)blockIdx.x * 256 + threadIdx.x) * 4;
    float4 v = *(const float4*)(mainp + i);
    const long b = i >> 21;                 // 2048*1024 per batch
    const long m = (i >> 10) & 2047;
    if (m >= 1024) {
        const float4 e = *(const float4*)(extrap + (i - (b + 1) * 1048576));
        v.x += e.x; v.y += e.y; v.z += e.z; v.w += e.w;
    }
    bf16x4 o;
    o[0] = (__bf16)v.x; o[1] = (__bf16)v.y; o[2] = (__bf16)v.z; o[3] = (__bf16)v.w;
    *(bf16x4*)(out + i) = o;
}

// ---------------- causal softmax row kernel (16B/lane) ----------------
__global__ __launch_bounds__(256) void softmax_causal(const __bf16* __restrict__ scores,
                                                      __bf16* __restrict__ P, float scale) {
    const int q = blockIdx.x;
    const long b = blockIdx.y;
    const __bf16* srow = scores + (b * SDIM + q) * (long)SDIM;
    __bf16* prow = P + (b * SDIM + q) * (long)SDIM;
    const int n = q + 1;
    const int tid = threadIdx.x;
    const int k0 = tid * 8;
    __shared__ float red[8];

    const bf16x8 v = *(const bf16x8*)(srow + k0);
    float vals[8];
    float mx = -1e30f;
    #pragma unroll
    for (int i = 0; i < 8; ++i) {
        const float s = (k0 + i < n) ? (float)v[i] * scale : -1e30f;
        vals[i] = s;
        mx = fmaxf(mx, s);
    }
    #pragma unroll
    for (int o = 32; o > 0; o >>= 1) mx = fmaxf(mx, __shfl_xor(mx, o));
    if ((tid & 63) == 0) red[tid >> 6] = mx;
    __syncthreads();
    mx = fmaxf(fmaxf(red[0], red[1]), fmaxf(red[2], red[3]));

    float p[8];
    float sum = 0.f;
    #pragma unroll
    for (int i = 0; i < 8; ++i) {
        p[i] = __expf(vals[i] - mx);
        sum += p[i];
    }
    #pragma unroll
    for (int o = 32; o > 0; o >>= 1) sum += __shfl_xor(sum, o);
    if ((tid & 63) == 0) red[4 + (tid >> 6)] = sum;
    __syncthreads();
    sum = red[4] + red[5] + red[6] + red[7];

    const float inv = 1.f / sum;
    bf16x8 o;
    #pragma unroll
    for (int i = 0; i < 8; ++i)
        o[i] = (__bf16)((k0 + i < n) ? p[i] * inv : 0.f);
    *(bf16x8*)(prow + k0) = o;
}

extern "C" void kernel_launch(void* const* d_in, const int* in_sizes, int n_in,
                              void* d_out, int out_size, void* d_ws, size_t ws_size,
                              hipStream_t stream) {
    const float* x  = (const float*)d_in[0];
    // d_in[1] = mask (tril ones) -- causality enforced by index, unused.
    const float* Wq = (const float*)d_in[2];
    const float* bq = (const float*)d_in[3];
    const float* Wk = (const float*)d_in[4];
    const float* bk = (const float*)d_in[5];
    const float* Wv = (const float*)d_in[6];
    const float* bv = (const float*)d_in[7];
    const float* Wo = (const float*)d_in[8];
    const float* bo = (const float*)d_in[9];
    float* out = (float*)d_out;

    char* ws = (char*)d_ws;
    const long MT = (long)BATCH * SDIM;           // 8192 rows
    const long XE = MT * BDIM;
    __bf16* xb    = (__bf16*)(ws);                // 16 MiB, dead after QKV
    __bf16* Wcat  = (__bf16*)(ws + 16777216);     // 6 MiB
    __bf16* Wot   = (__bf16*)(ws + 23068672);     // 2 MiB
    float*  bcat  = (float*)(ws + 25165824);      // 12 KiB
    __bf16* QKVb  = (__bf16*)(ws + 25178112);     // 48 MiB (8192 x 3072)
    __bf16* Vtb   = (__bf16*)(ws + 75509760);     // 16 MiB (B x [1024][2048])
    __bf16* Sc    = (__bf16*)(ws + 92286976);     // 32 MiB, dead after softmax
    __bf16* Pb    = (__bf16*)(ws + 25178112);     // alias QKVb[0..32M)
    float*  ctxM  = (float*)(ws + 92286976);      // 32 MiB fp32, alias Sc
    float*  ctxE  = (float*)(ws);                 // 16 MiB fp32, alias xb
    __bf16* ctxb  = (__bf16*)(ws + 58732544);     // 16 MiB, alias QKVb[32M..48M)

    const long SD  = (long)SDIM * BDIM;           // 2,097,152
    const long SS  = (long)SDIM * SDIM;           // 4,194,304
    const long SQ3 = (long)SDIM * 3 * BDIM;       // 6,291,456

    cvt_f32_bf16<<<dim3((unsigned)(XE / 4 / 256)), 256, 0, stream>>>(x, xb, XE);
    transpose_to_bf16<float><<<dim3(32, 32, 1), dim3(32, 8), 0, stream>>>(Wq, Wcat,             BDIM, BDIM, 0, 0);
    transpose_to_bf16<float><<<dim3(32, 32, 1), dim3(32, 8), 0, stream>>>(Wk, Wcat + 1024*1024, BDIM, BDIM, 0, 0);
    transpose_to_bf16<float><<<dim3(32, 32, 1), dim3(32, 8), 0, stream>>>(Wv, Wcat + 2048*1024, BDIM, BDIM, 0, 0);
    transpose_to_bf16<float><<<dim3(32, 32, 1), dim3(32, 8), 0, stream>>>(Wo, Wot,              BDIM, BDIM, 0, 0);
    concat3<<<dim3(12), 256, 0, stream>>>(bq, bk, bv, bcat);

    // QKV[8192][3072] = x @ Wcat^T + bcat   (384 blocks, XCD-swizzled, nbx=12)
    gemm8p<__bf16, false, false, true><<<dim3(384, 1, 1), 512, 0, stream>>>(
        xb, Wcat, QKVb, nullptr, bcat, BDIM, BDIM, BDIM, 3072, 12, 0, 0, 0);
    // V^T per batch: [S,1024] (stride 3072) -> [1024][S]
    transpose_to_bf16<__bf16><<<dim3(32, 64, BATCH), dim3(32, 8), 0, stream>>>(
        QKVb + 2048, Vtb, 3072, SDIM, SQ3, SD);
    // scores = Q @ K^T per batch (causal tile skip)
    gemm8p<__bf16, true, false, false><<<dim3(8, 8, BATCH), 512, 0, stream>>>(
        QKVb, QKVb + 1024, Sc, nullptr, nullptr, BDIM, 3072, 3072, SDIM, 8, SQ3, SQ3, SS);
    // causal softmax (scale = 1/32)
    softmax_causal<<<dim3(SDIM, BATCH), 256, 0, stream>>>(Sc, Pb, 0.03125f);
    // ctx = P @ V, K split into <=1024 chunks: bz = batch*2 + chunk
    gemm8p<float, false, true, false><<<dim3(4, 8, 2 * BATCH), 512, 0, stream>>>(
        Pb, Vtb, ctxM, ctxE, nullptr, SDIM, SDIM, SDIM, BDIM, 4, SS, SD, SD);
    // merge partials -> bf16 ctx
    merge_ctx<<<dim3((unsigned)(XE / 4 / 256)), 256, 0, stream>>>(ctxM, ctxE, ctxb);
    // out = ctx @ Wo + bo (fp32 out)
    gemm8p<float, false, false, false><<<dim3(4, 32, 1), 512, 0, stream>>>(
        ctxb, Wot, out, nullptr, bo, BDIM, BDIM, BDIM, BDIM, 4, 0, 0, 0);
}

// Round 8
// 241.133 us; speedup vs baseline: 1.1779x; 1.0621x over previous
//
#include <hip/hip_runtime.h>
#include <hip/hip_bf16.h>

// Attention: out = softmax_causal((xWq+bq)(xWk+bk)^T / sqrt(D)) (xWv+bv) Wo + bo
// B=4, S=2048, D=1024.  All GEMMs bf16 MFMA 16x16x32, fp32 accumulate.
// R8: R7's balanced 4-phase schedule with the RACE FIXED: wave->row mapping
//     remapped so fragment-half == staging-half (row = (m>>2)*128 + wm*64 +
//     (m&3)*16).  PH0/PH2 read only A-half0 (+B, both halves landed); PH1/PH3
//     read A-half1 (guarded by PH0's vmcnt(2)).  Counted vmcnt(2) only; one
//     2-load stage chunk per phase into buffer (T+1)&1; no mid-loop drains.

typedef __bf16 bf16x8 __attribute__((ext_vector_type(8)));
typedef __bf16 bf16x4 __attribute__((ext_vector_type(4)));
typedef float  f32x4  __attribute__((ext_vector_type(4)));

#define BDIM 1024
#define SDIM 2048
#define BATCH 4

#define BAR()  do { asm volatile("" ::: "memory"); __builtin_amdgcn_s_barrier(); \
                    asm volatile("" ::: "memory"); } while (0)
#define SCB()  __builtin_amdgcn_sched_barrier(0)
#define LGKM0() asm volatile("s_waitcnt lgkmcnt(0)" ::: "memory")

__device__ __forceinline__ void gload_lds16(const void* g, void* l) {
    __builtin_amdgcn_global_load_lds(
        (const __attribute__((address_space(1))) void*)g,
        (__attribute__((address_space(3))) void*)l, 16, 0, 0);
}

// ---------------- fp32 -> bf16 elementwise ----------------
__global__ __launch_bounds__(256) void cvt_f32_bf16(const float* __restrict__ in,
                                                    __bf16* __restrict__ out, long n) {
    long i = ((long)blockIdx.x * 256 + threadIdx.x) * 4;
    if (i + 3 < n) {
        float4 v = *(const float4*)(in + i);
        bf16x4 o;
        o[0] = (__bf16)v.x; o[1] = (__bf16)v.y; o[2] = (__bf16)v.z; o[3] = (__bf16)v.w;
        *(bf16x4*)(out + i) = o;
    }
}

// ---------------- bias concat [bq|bk|bv] -> bcat[3072] ----------------
__global__ __launch_bounds__(256) void concat3(const float* __restrict__ a,
                                               const float* __restrict__ b,
                                               const float* __restrict__ c,
                                               float* __restrict__ o) {
    int i = blockIdx.x * 256 + threadIdx.x;
    if (i < 3072)
        o[i] = (i < 1024) ? a[i] : ((i < 2048) ? b[i - 1024] : c[i - 2048]);
}

// ---------------- transpose (fp32 or bf16 in) -> bf16 out ----------------
template <typename Tin>
__global__ __launch_bounds__(256) void transpose_to_bf16(const Tin* __restrict__ in,
                                                         __bf16* __restrict__ out,
                                                         int ldIn, int ldOut,
                                                         long sIn, long sOut) {
    __shared__ float tile[32][33];
    const long b = blockIdx.z;
    in += b * sIn; out += b * sOut;
    const int r0 = blockIdx.y * 32, c0 = blockIdx.x * 32;
    const int tx = threadIdx.x, ty = threadIdx.y;  // block (32,8)
    #pragma unroll
    for (int j = ty; j < 32; j += 8)
        tile[j][tx] = (float)in[(long)(r0 + j) * ldIn + (c0 + tx)];
    __syncthreads();
    #pragma unroll
    for (int j = ty; j < 32; j += 8)
        out[(long)(c0 + j) * ldOut + (r0 + tx)] = (__bf16)tile[tx][j];
}

// ------------- 256x256 BT GEMM, BK=64, balanced 4-phase schedule -------------
// 8 waves (2M x 4N).  Wave wm owns C rows {wm*64..wm*64+63} U {128+wm*64..+63}
// (fragment-half == staging-half).  Per-wave output 128x64 = acc[8][4]:
//   acc[m][n]   (m=0..3): rows wm*64 + m*16        (A staging half 0)
//   acc[4+m][n] (m=0..3): rows 128 + wm*64 + m*16  (A staging half 1)
// Phase q: {4-8 ds_read_b128 | 2 gload_lds chunk of tile T+1 -> buf (T+1)&1 |
//           bar | lgkm0 | 16 MFMA | [vmcnt(2) at q0,q3] | bar}.
// Stage chunk order: A-h0(PH0) B-h0(PH1) B-h1(PH2) A-h1(PH3).
// Guard proof: T.PH3's vmcnt(2) -> A-h0/B-h0/B-h1(T+1) landed (A-h1 flies);
// PH0/PH2 read A-h0 + B (covered); T+1.PH0's vmcnt(2) -> A-h1(T+1) landed
// (only A-h0(T+2) remains out); PH1/PH3 read A-h1 (covered).  vmcnt never 0
// mid-loop; staging buffer != read buffer -> no lgkm drain needed.
// PVMODE: bz = batch*2 + chunk; K-range = [chunk*1024, min((by+1)*256,+1024));
template <typename Tout, bool CSKIP, bool PVMODE, bool SWZ>
__global__ __launch_bounds__(512, 2) void gemm4p(const __bf16* __restrict__ Ag,
                                                 const __bf16* __restrict__ Bg,
                                                 Tout* __restrict__ C0,
                                                 float* __restrict__ C1,
                                                 const float* __restrict__ bias,
                                                 int K, int lda, int ldb, int ldc,
                                                 int nbx, long sA, long sB, long sC) {
    int bx, by;
    const int bz = blockIdx.z;
    if (SWZ) {  // XCD-aware contiguous chunks (grid.x % 8 == 0)
        const int flat = blockIdx.x;
        const int w = (flat & 7) * ((int)gridDim.x >> 3) + (flat >> 3);
        bx = w % nbx; by = w / nbx;
    } else { bx = blockIdx.x; by = blockIdx.y; }
    if (CSKIP && bx > by) return;  // tile fully above causal diagonal

    const int m0 = by * 256, n0 = bx * 256;
    int kStart = 0, kEnd = K;
    const __bf16* A; const __bf16* B;
    Tout* C;
    if (PVMODE) {
        const int b = bz >> 1, chunk = bz & 1;
        kStart = chunk << 10;
        kEnd = min((by + 1) * 256, kStart + 1024);
        if (kEnd <= kStart) return;       // by<4 has no chunk1
        A = Ag + (long)b * sA;
        B = Bg + (long)b * sB;
        C = chunk ? (Tout*)(C1 + ((long)b - 1) * 1048576)  // rows shifted -1024
                  : C0 + (long)b * sC;
    } else {
        A = Ag + (long)bz * sA;
        B = Bg + (long)bz * sB;
        C = C0 + (long)bz * sC;
    }
    const int NT = (kEnd - kStart) >> 6;   // BK=64 tiles (always >= 4 here)

    __shared__ __align__(16) __bf16 As[2][16384];  // [256 rows][64 k], swizzled
    __shared__ __align__(16) __bf16 Bs[2][16384];

    const int tid = threadIdx.x;
    const int wid = tid >> 6, l = tid & 63;
    const int wm = wid >> 2, wn = wid & 3;          // wave grid 2(M) x 4(N)
    const int lr = l & 15, lu = l >> 4;

    // ---- staging source offsets (inverse-swizzled global cols, rule #21) ----
    int srcA[4], srcB[4];
    #pragma unroll
    for (int i = 0; i < 4; ++i) {
        const int beta = i * 8192 + tid * 16;          // linear LDS byte
        const int r = beta >> 7;                       // row 0..255 (128B rows)
        const int cb = (beta & 127) ^ ((r & 7) << 4);  // unswizzled col byte
        srcA[i] = (m0 + r) * lda + (cb >> 1);
        srcB[i] = (n0 + r) * ldb + (cb >> 1);
    }
    // one chunk = 2 gload_lds = 16 KB = one 128-row half of one operand tile
    auto stA = [&](int buf, int half, int koff) {
        #pragma unroll
        for (int i = 0; i < 2; ++i)
            gload_lds16(A + srcA[half * 2 + i] + koff,
                        (char*)&As[buf][0] + half * 16384 + i * 8192 + wid * 1024);
    };
    auto stB = [&](int buf, int half, int koff) {
        #pragma unroll
        for (int i = 0; i < 2; ++i)
            gload_lds16(B + srcB[half * 2 + i] + koff,
                        (char*)&Bs[buf][0] + half * 16384 + i * 8192 + wid * 1024);
    };

    // ---- swizzled fragment read offsets (elements), lane constants ----
    const int xo  = (lr & 7) << 4;                       // row-derived XOR (bytes)
    const int c0e = ((lu << 4) ^ xo) >> 1;               // kk=0 col elems
    const int c1e = ((64 + (lu << 4)) ^ xo) >> 1;        // kk=1 col elems
    const int aLo = (wm * 64 + lr) * 64;                 // A half-0 strip base
    const int aHi = (128 + wm * 64 + lr) * 64;           // A half-1 strip base
    const int bBase = (wn * 64 + lr) * 64;

    f32x4 acc[8][4] = {};
    bf16x8 aR[4], bR[4];

    // ---- prologue: stage tile 0 (A-h0, B-h0, B-h1, A-h1); need first 3 ----
    stA(0, 0, kStart); stB(0, 0, kStart); stB(0, 1, kStart); stA(0, 1, kStart);
    asm volatile("s_waitcnt vmcnt(2)" ::: "memory");   // A-h1 may still fly
    BAR();

    for (int T = 0; T < NT; ++T) {
        const int c = T & 1;
        const bool more = (T + 1 < NT);
        const int k1 = kStart + (T + 1) * 64;
        const __bf16* Ab = &As[c][0];
        const __bf16* Bb = &Bs[c][0];

        // ---- PH0: read A-h0 kk0 (4) + B kk0 (4) | stage A-h0(T+1) ----
        #pragma unroll
        for (int m = 0; m < 4; ++m) aR[m] = *(const bf16x8*)(Ab + aLo + m * 1024 + c0e);
        #pragma unroll
        for (int n = 0; n < 4; ++n) bR[n] = *(const bf16x8*)(Bb + bBase + n * 1024 + c0e);
        if (more) stA(c ^ 1, 0, k1);
        BAR();
        LGKM0(); SCB();
        __builtin_amdgcn_s_setprio(1);
        #pragma unroll
        for (int m = 0; m < 4; ++m)
            #pragma unroll
            for (int n = 0; n < 4; ++n)
                acc[m][n] = __builtin_amdgcn_mfma_f32_16x16x32_bf16(aR[m], bR[n],
                                                                    acc[m][n], 0, 0, 0);
        __builtin_amdgcn_s_setprio(0);
        if (more) asm volatile("s_waitcnt vmcnt(2)" ::: "memory");  // A-h1(T) landed
        else      asm volatile("s_waitcnt vmcnt(0)" ::: "memory");
        BAR();

        // ---- PH1: read A-h1 kk0 (4) | stage B-h0(T+1) ----
        #pragma unroll
        for (int m = 0; m < 4; ++m) aR[m] = *(const bf16x8*)(Ab + aHi + m * 1024 + c0e);
        if (more) stB(c ^ 1, 0, k1);
        BAR();
        LGKM0(); SCB();
        __builtin_amdgcn_s_setprio(1);
        #pragma unroll
        for (int m = 0; m < 4; ++m)
            #pragma unroll
            for (int n = 0; n < 4; ++n)
                acc[4 + m][n] = __builtin_amdgcn_mfma_f32_16x16x32_bf16(aR[m], bR[n],
                                                                        acc[4 + m][n], 0, 0, 0);
        __builtin_amdgcn_s_setprio(0);
        BAR();

        // ---- PH2: read A-h0 kk1 (4) + B kk1 (4) | stage B-h1(T+1) ----
        #pragma unroll
        for (int m = 0; m < 4; ++m) aR[m] = *(const bf16x8*)(Ab + aLo + m * 1024 + c1e);
        #pragma unroll
        for (int n = 0; n < 4; ++n) bR[n] = *(const bf16x8*)(Bb + bBase + n * 1024 + c1e);
        if (more) stB(c ^ 1, 1, k1);
        BAR();
        LGKM0(); SCB();
        __builtin_amdgcn_s_setprio(1);
        #pragma unroll
        for (int m = 0; m < 4; ++m)
            #pragma unroll
            for (int n = 0; n < 4; ++n)
                acc[m][n] = __builtin_amdgcn_mfma_f32_16x16x32_bf16(aR[m], bR[n],
                                                                    acc[m][n], 0, 0, 0);
        __builtin_amdgcn_s_setprio(0);
        BAR();

        // ---- PH3: read A-h1 kk1 (4) | stage A-h1(T+1) ----
        #pragma unroll
        for (int m = 0; m < 4; ++m) aR[m] = *(const bf16x8*)(Ab + aHi + m * 1024 + c1e);
        if (more) stA(c ^ 1, 1, k1);
        BAR();
        LGKM0(); SCB();
        __builtin_amdgcn_s_setprio(1);
        #pragma unroll
        for (int m = 0; m < 4; ++m)
            #pragma unroll
            for (int n = 0; n < 4; ++n)
                acc[4 + m][n] = __builtin_amdgcn_mfma_f32_16x16x32_bf16(aR[m], bR[n],
                                                                        acc[4 + m][n], 0, 0, 0);
        __builtin_amdgcn_s_setprio(0);
        if (more) {  // next tile's A-h0/B-h0/B-h1 landed; its A-h1 (last 2) flies
            asm volatile("s_waitcnt vmcnt(2)" ::: "memory");
            BAR();
        }
    }

    // epilogue: C/D layout col = lane&15, row = (lane>>4)*4 + reg [m89-verified]
    // acc index mi -> C row m0 + (mi>>2)*128 + wm*64 + (mi&3)*16 + rb
    const int rb = (l >> 4) * 4, cl = l & 15;
    #pragma unroll
    for (int n = 0; n < 4; ++n) {
        const int col = n0 + wn * 64 + n * 16 + cl;
        const float bvv = bias ? bias[col] : 0.f;
        #pragma unroll
        for (int mi = 0; mi < 8; ++mi) {
            const int row = m0 + (mi >> 2) * 128 + wm * 64 + (mi & 3) * 16 + rb;
            #pragma unroll
            for (int r = 0; r < 4; ++r)
                C[(long)(row + r) * ldc + col] = (Tout)(acc[mi][n][r] + bvv);
        }
    }
}

// ---------------- merge PV partials: ctxb = bf16(main + extra?) --------------
__global__ __launch_bounds__(256) void merge_ctx(const float* __restrict__ mainp,
                                                 const float* __restrict__ extrap,
                                                 __bf16* __restrict__ out) {
    const long i = ((long)blockIdx.x * 256 + threadIdx.x) * 4;
    float4 v = *(const float4*)(mainp + i);
    const long b = i >> 21;                 // 2048*1024 per batch
    const long m = (i >> 10) & 2047;
    if (m >= 1024) {
        const float4 e = *(const float4*)(extrap + (i - (b + 1) * 1048576));
        v.x += e.x; v.y += e.y; v.z += e.z; v.w += e.w;
    }
    bf16x4 o;
    o[0] = (__bf16)v.x; o[1] = (__bf16)v.y; o[2] = (__bf16)v.z; o[3] = (__bf16)v.w;
    *(bf16x4*)(out + i) = o;
}

// ---------------- causal softmax row kernel (16B/lane) ----------------
__global__ __launch_bounds__(256) void softmax_causal(const __bf16* __restrict__ scores,
                                                      __bf16* __restrict__ P, float scale) {
    const int q = blockIdx.x;
    const long b = blockIdx.y;
    const __bf16* srow = scores + (b * SDIM + q) * (long)SDIM;
    __bf16* prow = P + (b * SDIM + q) * (long)SDIM;
    const int n = q + 1;
    const int tid = threadIdx.x;
    const int k0 = tid * 8;
    __shared__ float red[8];

    const bf16x8 v = *(const bf16x8*)(srow + k0);
    float vals[8];
    float mx = -1e30f;
    #pragma unroll
    for (int i = 0; i < 8; ++i) {
        const float s = (k0 + i < n) ? (float)v[i] * scale : -1e30f;
        vals[i] = s;
        mx = fmaxf(mx, s);
    }
    #pragma unroll
    for (int o = 32; o > 0; o >>= 1) mx = fmaxf(mx, __shfl_xor(mx, o));
    if ((tid & 63) == 0) red[tid >> 6] = mx;
    __syncthreads();
    mx = fmaxf(fmaxf(red[0], red[1]), fmaxf(red[2], red[3]));

    float p[8];
    float sum = 0.f;
    #pragma unroll
    for (int i = 0; i < 8; ++i) {
        p[i] = __expf(vals[i] - mx);
        sum += p[i];
    }
    #pragma unroll
    for (int o = 32; o > 0; o >>= 1) sum += __shfl_xor(sum, o);
    if ((tid & 63) == 0) red[4 + (tid >> 6)] = sum;
    __syncthreads();
    sum = red[4] + red[5] + red[6] + red[7];

    const float inv = 1.f / sum;
    bf16x8 o;
    #pragma unroll
    for (int i = 0; i < 8; ++i)
        o[i] = (__bf16)((k0 + i < n) ? p[i] * inv : 0.f);
    *(bf16x8*)(prow + k0) = o;
}

extern "C" void kernel_launch(void* const* d_in, const int* in_sizes, int n_in,
                              void* d_out, int out_size, void* d_ws, size_t ws_size,
                              hipStream_t stream) {
    const float* x  = (const float*)d_in[0];
    // d_in[1] = mask (tril ones) -- causality enforced by index, unused.
    const float* Wq = (const float*)d_in[2];
    const float* bq = (const float*)d_in[3];
    const float* Wk = (const float*)d_in[4];
    const float* bk = (const float*)d_in[5];
    const float* Wv = (const float*)d_in[6];
    const float* bv = (const float*)d_in[7];
    const float* Wo = (const float*)d_in[8];
    const float* bo = (const float*)d_in[9];
    float* out = (float*)d_out;

    char* ws = (char*)d_ws;
    const long MT = (long)BATCH * SDIM;           // 8192 rows
    const long XE = MT * BDIM;
    __bf16* xb    = (__bf16*)(ws);                // 16 MiB, dead after QKV
    __bf16* Wcat  = (__bf16*)(ws + 16777216);     // 6 MiB
    __bf16* Wot   = (__bf16*)(ws + 23068672);     // 2 MiB
    float*  bcat  = (float*)(ws + 25165824);      // 12 KiB
    __bf16* QKVb  = (__bf16*)(ws + 25178112);     // 48 MiB (8192 x 3072)
    __bf16* Vtb   = (__bf16*)(ws + 75509760);     // 16 MiB (B x [1024][2048])
    __bf16* Sc    = (__bf16*)(ws + 92286976);     // 32 MiB, dead after softmax
    __bf16* Pb    = (__bf16*)(ws + 25178112);     // alias QKVb[0..32M)
    float*  ctxM  = (float*)(ws + 92286976);      // 32 MiB fp32, alias Sc
    float*  ctxE  = (float*)(ws);                 // 16 MiB fp32, alias xb
    __bf16* ctxb  = (__bf16*)(ws + 58732544);     // 16 MiB, alias QKVb[32M..48M)

    const long SD  = (long)SDIM * BDIM;           // 2,097,152
    const long SS  = (long)SDIM * SDIM;           // 4,194,304
    const long SQ3 = (long)SDIM * 3 * BDIM;       // 6,291,456

    cvt_f32_bf16<<<dim3((unsigned)(XE / 4 / 256)), 256, 0, stream>>>(x, xb, XE);
    transpose_to_bf16<float><<<dim3(32, 32, 1), dim3(32, 8), 0, stream>>>(Wq, Wcat,             BDIM, BDIM, 0, 0);
    transpose_to_bf16<float><<<dim3(32, 32, 1), dim3(32, 8), 0, stream>>>(Wk, Wcat + 1024*1024, BDIM, BDIM, 0, 0);
    transpose_to_bf16<float><<<dim3(32, 32, 1), dim3(32, 8), 0, stream>>>(Wv, Wcat + 2048*1024, BDIM, BDIM, 0, 0);
    transpose_to_bf16<float><<<dim3(32, 32, 1), dim3(32, 8), 0, stream>>>(Wo, Wot,              BDIM, BDIM, 0, 0);
    concat3<<<dim3(12), 256, 0, stream>>>(bq, bk, bv, bcat);

    // QKV[8192][3072] = x @ Wcat^T + bcat   (384 blocks, XCD-swizzled, nbx=12)
    gemm4p<__bf16, false, false, true><<<dim3(384, 1, 1), 512, 0, stream>>>(
        xb, Wcat, QKVb, nullptr, bcat, BDIM, BDIM, BDIM, 3072, 12, 0, 0, 0);
    // V^T per batch: [S,1024] (stride 3072) -> [1024][S]
    transpose_to_bf16<__bf16><<<dim3(32, 64, BATCH), dim3(32, 8), 0, stream>>>(
        QKVb + 2048, Vtb, 3072, SDIM, SQ3, SD);
    // scores = Q @ K^T per batch (causal tile skip)
    gemm4p<__bf16, true, false, false><<<dim3(8, 8, BATCH), 512, 0, stream>>>(
        QKVb, QKVb + 1024, Sc, nullptr, nullptr, BDIM, 3072, 3072, SDIM, 8, SQ3, SQ3, SS);
    // causal softmax (scale = 1/32)
    softmax_causal<<<dim3(SDIM, BATCH), 256, 0, stream>>>(Sc, Pb, 0.03125f);
    // ctx = P @ V, K split into <=1024 chunks: bz = batch*2 + chunk
    gemm4p<float, false, true, false><<<dim3(4, 8, 2 * BATCH), 512, 0, stream>>>(
        Pb, Vtb, ctxM, ctxE, nullptr, SDIM, SDIM, SDIM, BDIM, 4, SS, SD, SD);
    // merge partials -> bf16 ctx
    merge_ctx<<<dim3((unsigned)(XE / 4 / 256)), 256, 0, stream>>>(ctxM, ctxE, ctxb);
    // out = ctx @ Wo + bo (fp32 out)
    gemm4p<float, false, false, false><<<dim3(4, 32, 1), 512, 0, stream>>>(
        ctxb, Wot, out, nullptr, bo, BDIM, BDIM, BDIM, BDIM, 4, 0, 0, 0);
}

// Round 9
// 230.015 us; speedup vs baseline: 1.2348x; 1.0483x over previous
//
#include <hip/hip_runtime.h>
#include <hip/hip_bf16.h>

// Attention: out = softmax_causal((xWq+bq)(xWk+bk)^T / sqrt(D)) (xWv+bv) Wo + bo
// B=4, S=2048, D=1024.  All GEMMs bf16 MFMA 16x16x32, fp32 accumulate.
// R9: R8's proven 4-phase schedule, templated on BN (128/192/256) to fix grid
//     tails: QKV BN=192 (512 blocks = 2 exact rounds), out-proj BN=128 (256
//     blocks = full machine).  PV writes rows<1024 directly as bf16 (single
//     contributor); merge covers top half only.  Softmax skips masked loads
//     and stores beyond the 256-aligned causal boundary.

typedef __bf16 bf16x8 __attribute__((ext_vector_type(8)));
typedef __bf16 bf16x4 __attribute__((ext_vector_type(4)));
typedef float  f32x4  __attribute__((ext_vector_type(4)));

#define BDIM 1024
#define SDIM 2048
#define BATCH 4

#define BAR()  do { asm volatile("" ::: "memory"); __builtin_amdgcn_s_barrier(); \
                    asm volatile("" ::: "memory"); } while (0)
#define SCB()  __builtin_amdgcn_sched_barrier(0)
#define LGKM0() asm volatile("s_waitcnt lgkmcnt(0)" ::: "memory")

__device__ __forceinline__ void gload_lds16(const void* g, void* l) {
    __builtin_amdgcn_global_load_lds(
        (const __attribute__((address_space(1))) void*)g,
        (__attribute__((address_space(3))) void*)l, 16, 0, 0);
}

// ---------------- fp32 -> bf16 elementwise ----------------
__global__ __launch_bounds__(256) void cvt_f32_bf16(const float* __restrict__ in,
                                                    __bf16* __restrict__ out, long n) {
    long i = ((long)blockIdx.x * 256 + threadIdx.x) * 4;
    if (i + 3 < n) {
        float4 v = *(const float4*)(in + i);
        bf16x4 o;
        o[0] = (__bf16)v.x; o[1] = (__bf16)v.y; o[2] = (__bf16)v.z; o[3] = (__bf16)v.w;
        *(bf16x4*)(out + i) = o;
    }
}

// ---------------- bias concat [bq|bk|bv] -> bcat[3072] ----------------
__global__ __launch_bounds__(256) void concat3(const float* __restrict__ a,
                                               const float* __restrict__ b,
                                               const float* __restrict__ c,
                                               float* __restrict__ o) {
    int i = blockIdx.x * 256 + threadIdx.x;
    if (i < 3072)
        o[i] = (i < 1024) ? a[i] : ((i < 2048) ? b[i - 1024] : c[i - 2048]);
}

// ---------------- transpose (fp32 or bf16 in) -> bf16 out ----------------
template <typename Tin>
__global__ __launch_bounds__(256) void transpose_to_bf16(const Tin* __restrict__ in,
                                                         __bf16* __restrict__ out,
                                                         int ldIn, int ldOut,
                                                         long sIn, long sOut) {
    __shared__ float tile[32][33];
    const long b = blockIdx.z;
    in += b * sIn; out += b * sOut;
    const int r0 = blockIdx.y * 32, c0 = blockIdx.x * 32;
    const int tx = threadIdx.x, ty = threadIdx.y;  // block (32,8)
    #pragma unroll
    for (int j = ty; j < 32; j += 8)
        tile[j][tx] = (float)in[(long)(r0 + j) * ldIn + (c0 + tx)];
    __syncthreads();
    #pragma unroll
    for (int j = ty; j < 32; j += 8)
        out[(long)(c0 + j) * ldOut + (r0 + tx)] = (__bf16)tile[tx][j];
}

// ---------- 256 x BN BT GEMM, BK=64, balanced 4-phase (R8 schedule) ----------
// 8 waves (2M x 4N).  Per-wave output 128 x BN/4: acc[8][NF], NF = BN/64.
//   acc[m][n]   (m=0..3): rows wm*64 + m*16        (A staging half 0)
//   acc[4+m][n] (m=0..3): rows 128 + wm*64 + m*16  (A staging half 1)
// B tile = BN x 64, staged as NB = BN/64 single-gload chunks (8 KB each).
// Phase q: {ds_reads | stage chunk(s) of tile T+1 -> buf (T+1)&1 | bar |
//           lgkm0 | 4*NF MFMA | [vmcnt(2) at q0,q3] | bar}.
// Stage order: A-h0(PH0), B[0..NB1)(PH1), B[NB1..NB)(PH2), A-h1(PH3); only
// A-h1 is deferred past its tile boundary, so the R8 guard proof holds for
// any BN: T.PH3-end vmcnt(2) -> everything but A-h1 landed; T+1.PH0-end
// vmcnt(2) -> A-h1 landed.  vmcnt never 0 mid-loop.
// PVMODE: bz = batch*2 + chunk; K-range = [chunk*1024, min((by+1)*256,+1024));
//         rows<1024 (chunk0, by<4) have a single contributor -> write bf16
//         direct to C2; otherwise fp32 partials to C0/C1.
template <typename Tout, int BN, bool CSKIP, bool PVMODE, bool SWZ>
__global__ __launch_bounds__(512, 2) void gemm4p(const __bf16* __restrict__ Ag,
                                                 const __bf16* __restrict__ Bg,
                                                 Tout* __restrict__ C0,
                                                 float* __restrict__ C1,
                                                 __bf16* __restrict__ C2,
                                                 const float* __restrict__ bias,
                                                 int K, int lda, int ldb, int ldc,
                                                 int nbx, long sA, long sB, long sC) {
    constexpr int NF = BN / 64;        // B fragments per wave / B stage chunks
    constexpr int NB = BN / 64;
    constexpr int NB1 = (NB + 1) / 2;
    int bx, by;
    const int bz = blockIdx.z;
    if (SWZ) {  // XCD-aware contiguous chunks (grid.x % 8 == 0)
        const int flat = blockIdx.x;
        const int w = (flat & 7) * ((int)gridDim.x >> 3) + (flat >> 3);
        bx = w % nbx; by = w / nbx;
    } else { bx = blockIdx.x; by = blockIdx.y; }
    if (CSKIP && bx > by) return;  // tile fully above causal diagonal

    const int m0 = by * 256, n0 = bx * BN;
    int kStart = 0, kEnd = K;
    const __bf16* A; const __bf16* B;
    Tout* C;
    __bf16* Cd = nullptr;
    bool dwr = false;
    if (PVMODE) {
        const int b = bz >> 1, chunk = bz & 1;
        kStart = chunk << 10;
        kEnd = min((by + 1) * 256, kStart + 1024);
        if (kEnd <= kStart) return;       // by<4 has no chunk1
        A = Ag + (long)b * sA;
        B = Bg + (long)b * sB;
        dwr = (chunk == 0) && (by < 4);   // rows<1024: single contributor
        C = chunk ? (Tout*)(C1 + ((long)b - 1) * 1048576)  // rows shifted -1024
                  : C0 + (long)b * sC;
        Cd = C2 + (long)b * sC;
    } else {
        A = Ag + (long)bz * sA;
        B = Bg + (long)bz * sB;
        C = C0 + (long)bz * sC;
    }
    const int NT = (kEnd - kStart) >> 6;   // BK=64 tiles (always >= 4 here)

    __shared__ __align__(16) __bf16 As[2][16384];    // [256 rows][64 k], swz
    __shared__ __align__(16) __bf16 Bs[2][BN * 64];  // [BN rows][64 k], swz

    const int tid = threadIdx.x;
    const int wid = tid >> 6, l = tid & 63;
    const int wm = wid >> 2, wn = wid & 3;          // wave grid 2(M) x 4(N)
    const int lr = l & 15, lu = l >> 4;

    // ---- staging source offsets (inverse-swizzled global cols, rule #21) ----
    int srcA[4], srcB[NB];
    #pragma unroll
    for (int i = 0; i < 4; ++i) {
        const int beta = i * 8192 + tid * 16;          // linear LDS byte
        const int r = beta >> 7;                       // row (128B rows)
        const int cb = (beta & 127) ^ ((r & 7) << 4);  // unswizzled col byte
        srcA[i] = (m0 + r) * lda + (cb >> 1);
    }
    #pragma unroll
    for (int i = 0; i < NB; ++i) {
        const int beta = i * 8192 + tid * 16;
        const int r = beta >> 7;
        const int cb = (beta & 127) ^ ((r & 7) << 4);
        srcB[i] = (n0 + r) * ldb + (cb >> 1);
    }
    auto stA = [&](int buf, int half, int koff) {   // 2 gloads = one A half
        #pragma unroll
        for (int i = 0; i < 2; ++i)
            gload_lds16(A + srcA[half * 2 + i] + koff,
                        (char*)&As[buf][0] + (half * 2 + i) * 8192 + wid * 1024);
    };
    auto stB = [&](int buf, int j, int koff) {      // 1 gload = one B chunk
        gload_lds16(B + srcB[j] + koff,
                    (char*)&Bs[buf][0] + j * 8192 + wid * 1024);
    };

    // ---- swizzled fragment read offsets (elements), lane constants ----
    const int xo  = (lr & 7) << 4;                       // row-derived XOR
    const int c0e = ((lu << 4) ^ xo) >> 1;               // kk=0 col elems
    const int c1e = ((64 + (lu << 4)) ^ xo) >> 1;        // kk=1 col elems
    const int aLo = (wm * 64 + lr) * 64;                 // A half-0 strip base
    const int aHi = (128 + wm * 64 + lr) * 64;           // A half-1 strip base
    const int bBase = (wn * (BN / 4) + lr) * 64;

    f32x4 acc[8][NF] = {};
    bf16x8 aR[4], bR[NF];

    // ---- prologue: stage tile 0; A-h1 may stay in flight ----
    stA(0, 0, kStart);
    #pragma unroll
    for (int j = 0; j < NB; ++j) stB(0, j, kStart);
    stA(0, 1, kStart);
    asm volatile("s_waitcnt vmcnt(2)" ::: "memory");
    BAR();

    for (int T = 0; T < NT; ++T) {
        const int c = T & 1;
        const bool more = (T + 1 < NT);
        const int k1 = kStart + (T + 1) * 64;
        const __bf16* Ab = &As[c][0];
        const __bf16* Bb = &Bs[c][0];

        // ---- PH0: read A-h0 kk0 (4) + B kk0 (NF) | stage A-h0(T+1) ----
        #pragma unroll
        for (int m = 0; m < 4; ++m) aR[m] = *(const bf16x8*)(Ab + aLo + m * 1024 + c0e);
        #pragma unroll
        for (int n = 0; n < NF; ++n) bR[n] = *(const bf16x8*)(Bb + bBase + n * 1024 + c0e);
        if (more) stA(c ^ 1, 0, k1);
        BAR();
        LGKM0(); SCB();
        __builtin_amdgcn_s_setprio(1);
        #pragma unroll
        for (int m = 0; m < 4; ++m)
            #pragma unroll
            for (int n = 0; n < NF; ++n)
                acc[m][n] = __builtin_amdgcn_mfma_f32_16x16x32_bf16(aR[m], bR[n],
                                                                    acc[m][n], 0, 0, 0);
        __builtin_amdgcn_s_setprio(0);
        if (more) asm volatile("s_waitcnt vmcnt(2)" ::: "memory");  // A-h1(T) landed
        else      asm volatile("s_waitcnt vmcnt(0)" ::: "memory");
        BAR();

        // ---- PH1: read A-h1 kk0 (4) | stage B[0..NB1)(T+1) ----
        #pragma unroll
        for (int m = 0; m < 4; ++m) aR[m] = *(const bf16x8*)(Ab + aHi + m * 1024 + c0e);
        if (more) {
            #pragma unroll
            for (int j = 0; j < NB1; ++j) stB(c ^ 1, j, k1);
        }
        BAR();
        LGKM0(); SCB();
        __builtin_amdgcn_s_setprio(1);
        #pragma unroll
        for (int m = 0; m < 4; ++m)
            #pragma unroll
            for (int n = 0; n < NF; ++n)
                acc[4 + m][n] = __builtin_amdgcn_mfma_f32_16x16x32_bf16(aR[m], bR[n],
                                                                        acc[4 + m][n], 0, 0, 0);
        __builtin_amdgcn_s_setprio(0);
        BAR();

        // ---- PH2: read A-h0 kk1 (4) + B kk1 (NF) | stage B[NB1..NB)(T+1) ----
        #pragma unroll
        for (int m = 0; m < 4; ++m) aR[m] = *(const bf16x8*)(Ab + aLo + m * 1024 + c1e);
        #pragma unroll
        for (int n = 0; n < NF; ++n) bR[n] = *(const bf16x8*)(Bb + bBase + n * 1024 + c1e);
        if (more) {
            #pragma unroll
            for (int j = NB1; j < NB; ++j) stB(c ^ 1, j, k1);
        }
        BAR();
        LGKM0(); SCB();
        __builtin_amdgcn_s_setprio(1);
        #pragma unroll
        for (int m = 0; m < 4; ++m)
            #pragma unroll
            for (int n = 0; n < NF; ++n)
                acc[m][n] = __builtin_amdgcn_mfma_f32_16x16x32_bf16(aR[m], bR[n],
                                                                    acc[m][n], 0, 0, 0);
        __builtin_amdgcn_s_setprio(0);
        BAR();

        // ---- PH3: read A-h1 kk1 (4) | stage A-h1(T+1) ----
        #pragma unroll
        for (int m = 0; m < 4; ++m) aR[m] = *(const bf16x8*)(Ab + aHi + m * 1024 + c1e);
        if (more) stA(c ^ 1, 1, k1);
        BAR();
        LGKM0(); SCB();
        __builtin_amdgcn_s_setprio(1);
        #pragma unroll
        for (int m = 0; m < 4; ++m)
            #pragma unroll
            for (int n = 0; n < NF; ++n)
                acc[4 + m][n] = __builtin_amdgcn_mfma_f32_16x16x32_bf16(aR[m], bR[n],
                                                                        acc[4 + m][n], 0, 0, 0);
        __builtin_amdgcn_s_setprio(0);
        if (more) {  // next tile's A-h0 + all B landed; its A-h1 (last 2) flies
            asm volatile("s_waitcnt vmcnt(2)" ::: "memory");
            BAR();
        }
    }

    // epilogue: C/D layout col = lane&15, row = (lane>>4)*4 + reg [m89-verified]
    const int rb = (l >> 4) * 4, cl = l & 15;
    #pragma unroll
    for (int n = 0; n < NF; ++n) {
        const int col = n0 + wn * (BN / 4) + n * 16 + cl;
        const float bvv = bias ? bias[col] : 0.f;
        #pragma unroll
        for (int mi = 0; mi < 8; ++mi) {
            const int row = m0 + (mi >> 2) * 128 + wm * 64 + (mi & 3) * 16 + rb;
            #pragma unroll
            for (int r = 0; r < 4; ++r) {
                const float v = acc[mi][n][r] + bvv;
                if (PVMODE && dwr) Cd[(long)(row + r) * ldc + col] = (__bf16)v;
                else               C [(long)(row + r) * ldc + col] = (Tout)v;
            }
        }
    }
}

// -------- merge PV partials (top half rows only): ctxb = bf16(main+extra) ----
// main: [B][2048][1024] fp32 (rows 1024.. written); extra: [B][1024][1024] fp32.
__global__ __launch_bounds__(256) void merge_ctx(const float* __restrict__ mainp,
                                                 const float* __restrict__ extrap,
                                                 __bf16* __restrict__ out) {
    const long i = ((long)blockIdx.x * 256 + threadIdx.x) * 4;  // [0, XE/2)
    const long b = i >> 20;                  // 1024*1024 top-half elems/batch
    const long j = i & 1048575;
    const long gi = b * 2097152 + 1048576 + j;   // global ctx element
    float4 v = *(const float4*)(mainp + gi);
    const float4 e = *(const float4*)(extrap + b * 1048576 + j);
    v.x += e.x; v.y += e.y; v.z += e.z; v.w += e.w;
    bf16x4 o;
    o[0] = (__bf16)v.x; o[1] = (__bf16)v.y; o[2] = (__bf16)v.z; o[3] = (__bf16)v.w;
    *(bf16x4*)(out + gi) = o;
}

// ---------------- causal softmax row kernel (16B/lane, bounded I/O) ----------
__global__ __launch_bounds__(256) void softmax_causal(const __bf16* __restrict__ scores,
                                                      __bf16* __restrict__ P, float scale) {
    const int q = blockIdx.x;
    const long b = blockIdx.y;
    const __bf16* srow = scores + (b * SDIM + q) * (long)SDIM;
    __bf16* prow = P + (b * SDIM + q) * (long)SDIM;
    const int n = q + 1;
    const int kBound = ((q >> 8) + 1) << 8;    // PV reads P cols < kBound only
    const int tid = threadIdx.x;
    const int k0 = tid * 8;
    __shared__ float red[8];

    float vals[8];
    float mx = -1e30f;
    if (k0 < n) {
        const bf16x8 v = *(const bf16x8*)(srow + k0);
        #pragma unroll
        for (int i = 0; i < 8; ++i) {
            const float s = (k0 + i < n) ? (float)v[i] * scale : -1e30f;
            vals[i] = s;
            mx = fmaxf(mx, s);
        }
    } else {
        #pragma unroll
        for (int i = 0; i < 8; ++i) vals[i] = -1e30f;
    }
    #pragma unroll
    for (int o = 32; o > 0; o >>= 1) mx = fmaxf(mx, __shfl_xor(mx, o));
    if ((tid & 63) == 0) red[tid >> 6] = mx;
    __syncthreads();
    mx = fmaxf(fmaxf(red[0], red[1]), fmaxf(red[2], red[3]));

    float p[8];
    float sum = 0.f;
    #pragma unroll
    for (int i = 0; i < 8; ++i) {
        p[i] = __expf(vals[i] - mx);
        sum += p[i];
    }
    #pragma unroll
    for (int o = 32; o > 0; o >>= 1) sum += __shfl_xor(sum, o);
    if ((tid & 63) == 0) red[4 + (tid >> 6)] = sum;
    __syncthreads();
    sum = red[4] + red[5] + red[6] + red[7];

    if (k0 < kBound) {                     // cols >= kBound never read by PV
        const float inv = 1.f / sum;
        bf16x8 o;
        #pragma unroll
        for (int i = 0; i < 8; ++i)
            o[i] = (__bf16)((k0 + i < n) ? p[i] * inv : 0.f);
        *(bf16x8*)(prow + k0) = o;
    }
}

extern "C" void kernel_launch(void* const* d_in, const int* in_sizes, int n_in,
                              void* d_out, int out_size, void* d_ws, size_t ws_size,
                              hipStream_t stream) {
    const float* x  = (const float*)d_in[0];
    // d_in[1] = mask (tril ones) -- causality enforced by index, unused.
    const float* Wq = (const float*)d_in[2];
    const float* bq = (const float*)d_in[3];
    const float* Wk = (const float*)d_in[4];
    const float* bk = (const float*)d_in[5];
    const float* Wv = (const float*)d_in[6];
    const float* bv = (const float*)d_in[7];
    const float* Wo = (const float*)d_in[8];
    const float* bo = (const float*)d_in[9];
    float* out = (float*)d_out;

    char* ws = (char*)d_ws;
    const long MT = (long)BATCH * SDIM;           // 8192 rows
    const long XE = MT * BDIM;
    __bf16* xb    = (__bf16*)(ws);                // 16 MiB, dead after QKV
    __bf16* Wcat  = (__bf16*)(ws + 16777216);     // 6 MiB
    __bf16* Wot   = (__bf16*)(ws + 23068672);     // 2 MiB
    float*  bcat  = (float*)(ws + 25165824);      // 12 KiB
    __bf16* QKVb  = (__bf16*)(ws + 25178112);     // 48 MiB (8192 x 3072)
    __bf16* Vtb   = (__bf16*)(ws + 75509760);     // 16 MiB (B x [1024][2048])
    __bf16* Sc    = (__bf16*)(ws + 92286976);     // 32 MiB, dead after softmax
    __bf16* Pb    = (__bf16*)(ws + 25178112);     // alias QKVb[0..32M)
    float*  ctxM  = (float*)(ws + 92286976);      // 32 MiB fp32, alias Sc
    float*  ctxE  = (float*)(ws);                 // 16 MiB fp32, alias xb
    __bf16* ctxb  = (__bf16*)(ws + 58732544);     // 16 MiB, alias QKVb[32M..48M)

    const long SD  = (long)SDIM * BDIM;           // 2,097,152
    const long SS  = (long)SDIM * SDIM;           // 4,194,304
    const long SQ3 = (long)SDIM * 3 * BDIM;       // 6,291,456

    cvt_f32_bf16<<<dim3((unsigned)(XE / 4 / 256)), 256, 0, stream>>>(x, xb, XE);
    transpose_to_bf16<float><<<dim3(32, 32, 1), dim3(32, 8), 0, stream>>>(Wq, Wcat,             BDIM, BDIM, 0, 0);
    transpose_to_bf16<float><<<dim3(32, 32, 1), dim3(32, 8), 0, stream>>>(Wk, Wcat + 1024*1024, BDIM, BDIM, 0, 0);
    transpose_to_bf16<float><<<dim3(32, 32, 1), dim3(32, 8), 0, stream>>>(Wv, Wcat + 2048*1024, BDIM, BDIM, 0, 0);
    transpose_to_bf16<float><<<dim3(32, 32, 1), dim3(32, 8), 0, stream>>>(Wo, Wot,              BDIM, BDIM, 0, 0);
    concat3<<<dim3(12), 256, 0, stream>>>(bq, bk, bv, bcat);

    // QKV[8192][3072] = x @ Wcat^T + bcat   (BN=192: 32x16 = 512 blocks, swz)
    gemm4p<__bf16, 192, false, false, true><<<dim3(512, 1, 1), 512, 0, stream>>>(
        xb, Wcat, QKVb, nullptr, nullptr, bcat, BDIM, BDIM, BDIM, 3072, 16, 0, 0, 0);
    // V^T per batch: [S,1024] (stride 3072) -> [1024][S]
    transpose_to_bf16<__bf16><<<dim3(32, 64, BATCH), dim3(32, 8), 0, stream>>>(
        QKVb + 2048, Vtb, 3072, SDIM, SQ3, SD);
    // scores = Q @ K^T per batch (causal tile skip)
    gemm4p<__bf16, 256, true, false, false><<<dim3(8, 8, BATCH), 512, 0, stream>>>(
        QKVb, QKVb + 1024, Sc, nullptr, nullptr, nullptr, BDIM, 3072, 3072, SDIM, 8, SQ3, SQ3, SS);
    // causal softmax (scale = 1/32)
    softmax_causal<<<dim3(SDIM, BATCH), 256, 0, stream>>>(Sc, Pb, 0.03125f);
    // ctx = P @ V, K split into <=1024 chunks; rows<1024 written bf16 direct
    gemm4p<float, 256, false, true, false><<<dim3(4, 8, 2 * BATCH), 512, 0, stream>>>(
        Pb, Vtb, ctxM, ctxE, ctxb, nullptr, SDIM, SDIM, SDIM, BDIM, 4, SS, SD, SD);
    // merge fp32 partials (top-half rows only) -> bf16 ctx
    merge_ctx<<<dim3((unsigned)(XE / 2 / 4 / 256)), 256, 0, stream>>>(ctxM, ctxE, ctxb);
    // out = ctx @ Wo + bo (BN=128: 8x32 = 256 blocks, full machine, swz)
    gemm4p<float, 128, false, false, true><<<dim3(256, 1, 1), 512, 0, stream>>>(
        ctxb, Wot, out, nullptr, nullptr, bo, BDIM, BDIM, BDIM, BDIM, 8, 0, 0, 0);
}